// Round 7
// baseline (145.267 us; speedup 1.0000x reference)
//
#include <hip/hip_runtime.h>

namespace {
constexpr int Sdim = 128;
constexpr int Tdim = 64;
constexpr int U2c  = 16;
constexpr int PT   = 32;                 // pixel locations per block (128B yt rows)
constexpr int NTHREADS = 512;
constexpr int PP = Sdim * Sdim;          // 16384 pixels
constexpr int TQ = 16;                   // t-steps per stage (32 KiB per buffer)
constexpr int NSTG = Tdim / TQ;          // 4 stages

typedef float floatx4 __attribute__((ext_vector_type(4)));
}

// (512,2): 2 blocks/CU target; compiler VGPR budget 128 (R2 lesson: never over-clamp).
__global__ __launch_bounds__(NTHREADS, 2)
void upscale_fused(const float* __restrict__ yt,
                   const float* __restrict__ wgt,
                   const float* __restrict__ bias,
                   float* __restrict__ out)
{
    // Double-buffered weight tile, layout [t][u][col], col = p ^ (4*(t&7)).
    // Compute reads: ds_read_b128 per (t,u): 8 distinct quad-addrs (pg 0..7)
    // covering all 32 banks, 8-way same-address broadcast across b-lanes -> free.
    __shared__ float wlds[2][TQ * U2c * PT];   // 64 KiB total

    const int tid   = threadIdx.x;
    const int p_blk = blockIdx.x * PT;

    const int pg = tid & 7;            // 4 p's: p0..p0+3
    const int bb = tid >> 3;           // 1 b: 0..63  (wave = 8 pg x 8 b, no dup)
    const int p0 = p_blk + pg * 4;

    const float4* wgt4 = reinterpret_cast<const float4*>(wgt);

    // ---- staging: global->reg (issued a full stage early), reg->LDS late --------
    float4 sreg[4];
    auto stage_load = [&](int stg) {
        #pragma unroll
        for (int i = 0; i < 4; ++i) {
            const int f = i * NTHREADS + tid;    // 0..2047 float4s of the 32KB tile
            const int r = f >> 6;                // p row 0..31
            const int c = f & 63;                // float4 within the 1KB p-row
            sreg[i] = wgt4[(size_t)(p_blk + r) * 256 + (size_t)stg * 64 + c];
        }
    };
    auto stage_write = [&](int buf) {
        #pragma unroll
        for (int i = 0; i < 4; ++i) {
            const int f = i * NTHREADS + tid;
            const int r = f >> 6;
            const int c = f & 63;
            const int tw = c >> 2;               // t_local 0..15
            const int uq = c & 3;                // u quad
            const int col = r ^ (4 * (tw & 7));  // quad-preserving XOR swizzle
            float* dst = &wlds[buf][(tw * U2c + uq * 4) * PT + col];
            dst[0 * PT] = sreg[i].x;  dst[1 * PT] = sreg[i].y;
            dst[2 * PT] = sreg[i].z;  dst[3 * PT] = sreg[i].w;
        }
    };

    stage_load(0);

    // ---- init acc with bias ------------------------------------------------------
    float acc[4][16];   // [p_local][u]
    #pragma unroll
    for (int j = 0; j < 4; ++j) {
        const float* bp = bias + (size_t)(p0 + j) * U2c;
        #pragma unroll
        for (int q = 0; q < 4; ++q) {
            const float4 v = *reinterpret_cast<const float4*>(bp + q * 4);
            acc[j][q * 4 + 0] = v.x;  acc[j][q * 4 + 1] = v.y;
            acc[j][q * 4 + 2] = v.z;  acc[j][q * 4 + 3] = v.w;
        }
    }

    // ---- yt: ONE float4 per thread per t-step: 1024B/instr, 8x128B segments ------
    const float* yb = yt + (size_t)bb * ((size_t)Tdim * PP) + p0;
    auto ldy = [&](int t) {
        return *reinterpret_cast<const float4*>(yb + (size_t)t * PP);
    };

    auto step = [&](const float4& y, int buf, int tl) {
        const float* wbase = &wlds[buf][(size_t)tl * (U2c * PT) + ((pg * 4) ^ (4 * (tl & 7)))];
        #pragma unroll
        for (int u = 0; u < 16; ++u) {
            const float4 wv = *reinterpret_cast<const float4*>(wbase + u * PT);
            acc[0][u] = fmaf(y.x, wv.x, acc[0][u]);
            acc[1][u] = fmaf(y.y, wv.y, acc[1][u]);
            acc[2][u] = fmaf(y.z, wv.z, acc[2][u]);
            acc[3][u] = fmaf(y.w, wv.w, acc[3][u]);
        }
    };

    // ---- depth-4 static ping-pong yt ring ----------------------------------------
    float4 A = ldy(0), B = ldy(1), C = ldy(2), D = ldy(3);

    stage_write(0);
    __syncthreads();     // stage 0 visible

    #pragma unroll 1
    for (int stg = 0; stg < NSTG; ++stg) {
        const int buf = stg & 1;
        #pragma unroll 1
        for (int tq = 0; tq < TQ; tq += 4) {
            const int tg = stg * TQ + tq;
            step(A, buf, tq + 0); if (tg + 4 < Tdim) A = ldy(tg + 4);
            step(B, buf, tq + 1); if (tg + 5 < Tdim) B = ldy(tg + 5);
            step(C, buf, tq + 2); if (tg + 6 < Tdim) C = ldy(tg + 6);
            step(D, buf, tq + 3); if (tg + 7 < Tdim) D = ldy(tg + 7);
            // issue next stage's weight loads after the first quad: decoupled from
            // both the ring waits (older ring loads consumed first) and the write
            // (12 t-steps of slack to return)
            if (tq == 0 && stg + 1 < NSTG) stage_load(stg + 1);
        }
        if (stg + 1 < NSTG) {
            stage_write(buf ^ 1);   // other buffer: fully consumed one barrier ago
            __syncthreads();        // ONE barrier per stage
        }
    }

    // ---- epilogue: 4 rows x 64B contiguous per thread, nontemporal ---------------
    const int s1    = p_blk / Sdim;
    const int s2_0  = p_blk % Sdim;
    const int cbase = (s2_0 + pg * 4) * 4;
    float* ob = out + (size_t)bb * (512 * 512);

    #pragma unroll
    for (int u1 = 0; u1 < 4; ++u1) {
        const int r = s1 * 4 + u1;
        float* rp = ob + (size_t)r * 512 + cbase;
        #pragma unroll
        for (int j = 0; j < 4; ++j) {
            floatx4 v;
            v.x = acc[j][u1 * 4 + 0];
            v.y = acc[j][u1 * 4 + 1];
            v.z = acc[j][u1 * 4 + 2];
            v.w = acc[j][u1 * 4 + 3];
            __builtin_nontemporal_store(v, reinterpret_cast<floatx4*>(rp + j * 4));
        }
    }
}

extern "C" void kernel_launch(void* const* d_in, const int* in_sizes, int n_in,
                              void* d_out, int out_size, void* d_ws, size_t ws_size,
                              hipStream_t stream)
{
    const float* yt   = (const float*)d_in[0];
    const float* wgt  = (const float*)d_in[1];
    const float* bias = (const float*)d_in[2];
    float* outp       = (float*)d_out;

    dim3 grid(PP / PT);     // 512 blocks
    dim3 block(NTHREADS);
    hipLaunchKernelGGL(upscale_fused, grid, block, 0, stream, yt, wgt, bias, outp);
}